// Round 15
// baseline (139.693 us; speedup 1.0000x reference)
//
#include <hip/hip_runtime.h>

// ---------------------------------------------------------------------------
// MoE gated MLP with LoRA, top-2 of 8, T=512, H=2048, I=1024, R=16.
// Round 14: R13 with ONE change: gemm1 BN 64g+64u -> 32g+32u (ct 0..31,
// grid 1024). Active gemm1 blocks ~130 -> ~260 = all 256 CUs pulling
// weights concurrently; B panels still read exactly once (ct tiles
// disjoint); only the small cache-resident A panel is re-read 2x.
// ---------------------------------------------------------------------------

typedef short  s16x8 __attribute__((ext_vector_type(8)));
typedef float  f32x4 __attribute__((ext_vector_type(4)));
typedef unsigned short u16x4 __attribute__((ext_vector_type(4)));
typedef unsigned short u16x8 __attribute__((ext_vector_type(8)));

__device__ __forceinline__ unsigned short f2bf(float f) {
  unsigned u = __builtin_bit_cast(unsigned, f);
  u += 0x7fffu + ((u >> 16) & 1u);          // RNE
  return (unsigned short)(u >> 16);
}

// Barrier that does NOT drain vmcnt.
#define PIPE_BARRIER() asm volatile("s_waitcnt lgkmcnt(0)\n\ts_barrier" ::: "memory")

// ---- workspace layout (bytes). [0, ZERO_SPAN) memset to 0 each launch ----
#define OFF_CNT    0u          // 8 int (pad 256)
#define ZERO_SPAN  256u
#define OFF_LIST   256u        // 8*512 int = 16384
#define OFF_PW     16640u      // 1024 f32 = 4096
#define OFF_WG     20736u      // 8*2048 f32 = 65536
#define OFF_XBF    86272u      // 512*2048 bf16 = 2097152
#define OFF_H      2183424u    // 1024*1024 bf16 = 2097152
// total ~4.3 MB

// ---------------------------------------------------------------------------
__global__ void k_gatecomb(const float* __restrict__ gw, const float* __restrict__ gA,
                           const float* __restrict__ gB, float* __restrict__ Wg) {
  int idx = blockIdx.x * 256 + threadIdx.x;   // 16384
  int e = idx >> 11, h = idx & 2047;
  float acc = gw[idx];
#pragma unroll
  for (int r = 0; r < 16; ++r)
    acc += 2.0f * gB[e * 16 + r] * gA[r * 2048 + h];
  Wg[idx] = acc;
}

// fp32 router (exact logits -> identical top-k to reference) + fused x->bf16.
__global__ void k_router(const float* __restrict__ x, const float* __restrict__ Wg,
                         int* __restrict__ cnt, int* __restrict__ list,
                         float* __restrict__ pw, unsigned short* __restrict__ xbf) {
  int t = blockIdx.x, tid = threadIdx.x;
  __shared__ float xs[2048];
  __shared__ float logits[8];
  for (int i = tid; i < 2048; i += 256) xs[i] = x[(size_t)t * 2048 + i];
  __syncthreads();
  {
    u16x8 o;
#pragma unroll
    for (int j = 0; j < 8; ++j) o[j] = f2bf(xs[tid * 8 + j]);
    *(u16x8*)(xbf + (size_t)t * 2048 + tid * 8) = o;
  }
  int e = tid >> 5, l = tid & 31;
  float s = 0.f;
  for (int h = l; h < 2048; h += 32) s += xs[h] * Wg[e * 2048 + h];
#pragma unroll
  for (int off = 16; off >= 1; off >>= 1) s += __shfl_down(s, off, 32);
  if (l == 0) logits[e] = s;
  __syncthreads();
  if (tid == 0) {
    float m = logits[0];
#pragma unroll
    for (int i = 1; i < 8; ++i) m = fmaxf(m, logits[i]);
    float ex[8];
#pragma unroll
    for (int i = 0; i < 8; ++i) ex[i] = __expf(logits[i] - m);
    int e1 = 0; float v1 = ex[0];
#pragma unroll
    for (int i = 1; i < 8; ++i) if (ex[i] > v1) { v1 = ex[i]; e1 = i; }
    int e2 = -1; float v2 = -1.f;
#pragma unroll
    for (int i = 0; i < 8; ++i) if (i != e1 && ex[i] > v2) { v2 = ex[i]; e2 = i; }
    float inv = 1.f / (v1 + v2);
    int p1 = 2 * t, p2 = 2 * t + 1;
    pw[p1] = v1 * inv;
    pw[p2] = v2 * inv;
    int s1 = atomicAdd(&cnt[e1], 1); list[e1 * 512 + s1] = p1;
    int s2 = atomicAdd(&cnt[e2], 1); list[e2 * 512 + s2] = p2;
  }
}

// ---------------------------------------------------------------------------
// GEMM1: gathered x rows [BM=128] x gup[e] (32 gate + 32 up cols), full
// K=2048 (NT=32), 3-deep register pipeline, 8 waves = 4M x 2N.
// FUSED ter1 = x . gupA[e] (ni==0 waves). Epilogue: silu(g+2dg)*(u+2du) -> h.
__global__ __launch_bounds__(512) void k_gemm1(
    const unsigned short* __restrict__ xbf, const float* __restrict__ gup,
    const float* __restrict__ gupA, const float* __restrict__ gupB,
    const int* __restrict__ cnt, const int* __restrict__ list,
    unsigned short* __restrict__ h) {
  const int id = blockIdx.x;                 // 0..1023
  const int e  = id & 7;
  const int m  = id >> 3;
  const int ct = m & 31;                     // i-cols [ct*32, ct*32+32)
  const int st = m >> 5;                     // 0..3
  const int n = cnt[e];
  if (st * 128 >= n) return;
  const int tid = threadIdx.x;

  __shared__ unsigned short Ap[2][128 * 64];   // [row][k] swizzled
  __shared__ unsigned short Bp[2][64 * 64];    // [col][k]: 0..31 gate, 32..63 up
  __shared__ unsigned short Bp2[2][16 * 64];   // gupA [r][k]

  const int c0 = ct * 32;

  const unsigned short *aSrc0, *aSrc1;
  int aOff0, aOff1;
  {
    int row = tid >> 3, k16 = tid & 7;
    int p = list[e * 512 + min(st * 128 + row, n - 1)];
    aSrc0 = xbf + (size_t)(p >> 1) * 2048 + k16 * 8;
    aOff0 = row * 64 + ((k16 * 8) ^ ((row & 7) << 3));
    int slot = tid + 512;
    row = slot >> 3; k16 = slot & 7;
    p = list[e * 512 + min(st * 128 + row, n - 1)];
    aSrc1 = xbf + (size_t)(p >> 1) * 2048 + k16 * 8;
    aOff1 = row * 64 + ((k16 * 8) ^ ((row & 7) << 3));
  }
  // B: thread owns col pair (c2, c2+1) x 4 k-rows (kr4..kr4+3).
  // Pair never straddles the gate/up boundary (32, even).
  const int c2  = (tid & 31) * 2;            // 0..62
  const int kr4 = (tid >> 5) * 4;            // 0..60
  const int gcg2 = (c2 < 32) ? (c0 + c2) : (1024 + c0 + c2 - 32);
  const float* bSrc = gup + (size_t)e * 2048 * 2048 + (size_t)kr4 * 2048 + gcg2;
  // kr4 is 4-aligned; XOR value is 8-aligned; kr4+j (j<4) never crosses bit 3
  const int bOff0 = c2 * 64 + (kr4 ^ ((c2 & 7) << 3));
  const int bOff1 = (c2 + 1) * 64 + (kr4 ^ (((c2 + 1) & 7) << 3));

  // gupA sub-tile staging (threads 0..127): 16 r x 8 k-chunks
  const int gr = (tid >> 3) & 15, gk = tid & 7;
  const float* gaSrc = gupA + ((size_t)e * 16 + gr) * 2048 + gk * 8;
  const int gaOff = gr * 64 + ((gk * 8) ^ ((gr & 7) << 3));

  const int lane = tid & 63, wv = tid >> 6;
  const int lr = lane & 15, lh = lane >> 4;
  const int wr = wv >> 1, ni = wv & 1;       // 4 M-waves x 2 N-waves

  uint4 a0A, a1A, a0B, a1B, a0C, a1C;
  float2 bA[4], bB[4], bC[4];
  float4 g0A, g1A, g0B, g1B, g0C, g1C;

#define G1_LOAD(SUF, T) {                                        \
    const int kk = (T) * 64;                                     \
    a0##SUF = *(const uint4*)(aSrc0 + kk);                       \
    a1##SUF = *(const uint4*)(aSrc1 + kk);                       \
    _Pragma("unroll") for (int j = 0; j < 4; ++j)                \
      b##SUF[j] = *(const float2*)(bSrc + (size_t)(kk + j) * 2048); \
    if (tid < 128) {                                             \
      g0##SUF = *(const float4*)(gaSrc + kk);                    \
      g1##SUF = *(const float4*)(gaSrc + kk + 4); } }

#define G1_BODY(BUF, SUF, NXT) {                                               \
    *(uint4*)&Ap[BUF][aOff0] = a0##SUF;                                        \
    *(uint4*)&Ap[BUF][aOff1] = a1##SUF;                                        \
    { u16x4 o0, o1;                                                            \
      _Pragma("unroll") for (int j = 0; j < 4; ++j) {                          \
        o0[j] = f2bf(b##SUF[j].x); o1[j] = f2bf(b##SUF[j].y); }                \
      *(u16x4*)&Bp[BUF][bOff0] = o0;                                           \
      *(u16x4*)&Bp[BUF][bOff1] = o1; }                                         \
    if (tid < 128) { u16x8 og;                                                 \
      og[0]=f2bf(g0##SUF.x); og[1]=f2bf(g0##SUF.y);                            \
      og[2]=f2bf(g0##SUF.z); og[3]=f2bf(g0##SUF.w);                            \
      og[4]=f2bf(g1##SUF.x); og[5]=f2bf(g1##SUF.y);                            \
      og[6]=f2bf(g1##SUF.z); og[7]=f2bf(g1##SUF.w);                            \
      *(u16x8*)&Bp2[BUF][gaOff] = og; }                                        \
    PIPE_BARRIER();                                                            \
    if ((NXT) < 32) G1_LOAD(SUF, NXT);                                         \
    _Pragma("unroll") for (int ks = 0; ks < 64; ks += 32) {                    \
      int kb = ks + lh * 8;                                                    \
      s16x8 af[2], bg, bu, bt;                                                 \
      _Pragma("unroll") for (int q = 0; q < 2; ++q) {                          \
        int ar = wr * 32 + q * 16 + lr;                                        \
        af[q] = *(const s16x8*)&Ap[BUF][ar * 64 + (kb ^ ((ar & 7) << 3))];     \
      }                                                                        \
      { int bc = ni * 16 + lr;                                                 \
        int kx = kb ^ ((bc & 7) << 3);                                         \
        bg = *(const s16x8*)&Bp[BUF][bc * 64 + kx];                            \
        bu = *(const s16x8*)&Bp[BUF][(bc + 32) * 64 + kx]; }                   \
      _Pragma("unroll") for (int q = 0; q < 2; ++q) {                          \
        accg[q] = __builtin_amdgcn_mfma_f32_16x16x32_bf16(af[q], bg, accg[q], 0, 0, 0); \
        accu[q] = __builtin_amdgcn_mfma_f32_16x16x32_bf16(af[q], bu, accu[q], 0, 0, 0); \
      }                                                                        \
      if (ni == 0) {                                                           \
        bt = *(const s16x8*)&Bp2[BUF][lr * 64 + (kb ^ ((lr & 7) << 3))];       \
        _Pragma("unroll") for (int q = 0; q < 2; ++q)                          \
          acct1[q] = __builtin_amdgcn_mfma_f32_16x16x32_bf16(af[q], bt, acct1[q], 0, 0, 0); \
      }                                                                        \
    } }

  f32x4 accg[2] = {}, accu[2] = {};
  f32x4 acct1[2] = {};
  G1_LOAD(A, 0);
  G1_LOAD(B, 1);
  G1_LOAD(C, 2);
  for (int tt = 0; tt < 30; tt += 6) {
    G1_BODY(0, A, tt + 3);
    G1_BODY(1, B, tt + 4);
    G1_BODY(0, C, tt + 5);
    G1_BODY(1, A, tt + 6);
    G1_BODY(0, B, tt + 7);
    G1_BODY(1, C, tt + 8);
  }
  G1_BODY(0, A, 99);   // tile 30
  G1_BODY(1, B, 99);   // tile 31
#undef G1_LOAD
#undef G1_BODY

  // ---- epilogue: dump in-register ter1 to LDS, fuse LoRA + silu, store h ----
  __syncthreads();
  float* tlds = (float*)&Ap[0][0];             // 128 x 16 f32
  if (ni == 0) {
#pragma unroll
    for (int q = 0; q < 2; ++q)
#pragma unroll
      for (int j = 0; j < 4; ++j) {
        int row = wr * 32 + q * 16 + lh * 4 + j;
        tlds[row * 16 + lr] = acct1[q][j];
      }
  }
  __syncthreads();
  {
    int gc = c0 + ni * 16 + lr;                // global i-col 0..1023
    const float4* g4 = (const float4*)(gupB + ((size_t)e * 2048 + gc) * 16);
    const float4* u4 = (const float4*)(gupB + ((size_t)e * 2048 + 1024 + gc) * 16);
    float gv2[16], uv2[16];
#pragma unroll
    for (int q = 0; q < 4; ++q) {
      float4 gv = g4[q], uv = u4[q];
      gv2[q*4+0]=gv.x; gv2[q*4+1]=gv.y; gv2[q*4+2]=gv.z; gv2[q*4+3]=gv.w;
      uv2[q*4+0]=uv.x; uv2[q*4+1]=uv.y; uv2[q*4+2]=uv.z; uv2[q*4+3]=uv.w;
    }
#pragma unroll
    for (int q = 0; q < 2; ++q) {
#pragma unroll
      for (int j = 0; j < 4; ++j) {
        int row = wr * 32 + q * 16 + lh * 4 + j;
        if (st * 128 + row < n) {
          int p = list[e * 512 + st * 128 + row];
          const float* tv = &tlds[row * 16];
          float dg = 0.f, du = 0.f;
#pragma unroll
          for (int rr = 0; rr < 16; ++rr) { dg += tv[rr] * gv2[rr]; du += tv[rr] * uv2[rr]; }
          float g = accg[q][j] + 2.f * dg;
          float u = accu[q][j] + 2.f * du;
          h[(size_t)p * 1024 + gc] = f2bf(g / (1.f + __expf(-g)) * u);
        }
      }
    }
  }
}

// ---------------------------------------------------------------------------
// GEMM2: gathered h rows [BM=128] x down[e] [BN=64], full K=1024 (NT=16),
// 3-deep pipeline. FUSED: ter2 = h . dlA[e] as +2 MFMA/body (Bp2 tile).
// Epilogue fuses down-LoRA + routing weight; atomicAdd into zeroed y.
__global__ __launch_bounds__(512) void k_gemm2(
    const unsigned short* __restrict__ h, const float* __restrict__ down,
    const float* __restrict__ dlA, const float* __restrict__ dlB,
    const int* __restrict__ cnt, const int* __restrict__ list,
    const float* __restrict__ pw, float* __restrict__ y) {
  const int id = blockIdx.x;                 // 0..1023
  const int e  = id & 7;
  const int m  = id >> 3;
  const int ct = m & 31;                     // 0..31
  const int st = m >> 5;                     // 0..3
  const int n = cnt[e];
  if (st * 128 >= n) return;
  const int tid = threadIdx.x;

  __shared__ unsigned short Ap[2][128 * 64];
  __shared__ unsigned short Bp[2][64 * 64];
  __shared__ unsigned short Bp2[2][16 * 64];   // dlA [r][k]

  const int c0 = ct * 64;

  const unsigned short *aSrc0, *aSrc1;
  int aOff0, aOff1;
  {
    int row = tid >> 3, k16 = tid & 7;
    int p = list[e * 512 + min(st * 128 + row, n - 1)];
    aSrc0 = h + (size_t)p * 1024 + k16 * 8;
    aOff0 = row * 64 + ((k16 * 8) ^ ((row & 7) << 3));
    int slot = tid + 512;
    row = slot >> 3; k16 = slot & 7;
    p = list[e * 512 + min(st * 128 + row, n - 1)];
    aSrc1 = h + (size_t)p * 1024 + k16 * 8;
    aOff1 = row * 64 + ((k16 * 8) ^ ((row & 7) << 3));
  }
  const int bcol = tid & 63, kg = tid >> 6;  // 8 k-groups of 8
  const float* bSrc = down + (size_t)e * 1024 * 2048 + (size_t)(kg * 8) * 2048 + c0 + bcol;
  const int bOff = bcol * 64 + ((kg * 8) ^ ((bcol & 7) << 3));

  // dlA sub-tile staging (threads 0..127): 16 r x 8 k-chunks
  const int gr = (tid >> 3) & 15, gk = tid & 7;
  const float* gaSrc = dlA + ((size_t)e * 16 + gr) * 1024 + gk * 8;
  const int gaOff = gr * 64 + ((gk * 8) ^ ((gr & 7) << 3));

  const int lane = tid & 63, wv = tid >> 6;
  const int lr = lane & 15, lh = lane >> 4;
  const int wr = wv >> 1, ni = wv & 1;

  uint4 a0A, a1A, a0B, a1B, a0C, a1C;
  float bA[8], bB[8], bC[8];
  float4 g0A, g1A, g0B, g1B, g0C, g1C;

#define G2_LOAD(SUF, T) {                                        \
    const int kk = (T) * 64;                                     \
    a0##SUF = *(const uint4*)(aSrc0 + kk);                       \
    a1##SUF = *(const uint4*)(aSrc1 + kk);                       \
    _Pragma("unroll") for (int j = 0; j < 8; ++j)                \
      b##SUF[j] = bSrc[(size_t)(kk + j) * 2048];                 \
    if (tid < 128) {                                             \
      g0##SUF = *(const float4*)(gaSrc + kk);                    \
      g1##SUF = *(const float4*)(gaSrc + kk + 4); } }

#define G2_BODY(BUF, SUF, NXT) {                                               \
    *(uint4*)&Ap[BUF][aOff0] = a0##SUF;                                        \
    *(uint4*)&Ap[BUF][aOff1] = a1##SUF;                                        \
    { u16x8 o;                                                                 \
      _Pragma("unroll") for (int j = 0; j < 8; ++j) o[j] = f2bf(b##SUF[j]);    \
      *(u16x8*)&Bp[BUF][bOff] = o; }                                           \
    if (tid < 128) { u16x8 og;                                                 \
      og[0]=f2bf(g0##SUF.x); og[1]=f2bf(g0##SUF.y);                            \
      og[2]=f2bf(g0##SUF.z); og[3]=f2bf(g0##SUF.w);                            \
      og[4]=f2bf(g1##SUF.x); og[5]=f2bf(g1##SUF.y);                            \
      og[6]=f2bf(g1##SUF.z); og[7]=f2bf(g1##SUF.w);                            \
      *(u16x8*)&Bp2[BUF][gaOff] = og; }                                        \
    PIPE_BARRIER();                                                            \
    if ((NXT) < 16) G2_LOAD(SUF, NXT);                                         \
    _Pragma("unroll") for (int ks = 0; ks < 64; ks += 32) {                    \
      int kb = ks + lh * 8;                                                    \
      s16x8 af[2], bd[2], bt;                                                  \
      _Pragma("unroll") for (int q = 0; q < 2; ++q) {                          \
        int ar = wr * 32 + q * 16 + lr;                                        \
        af[q] = *(const s16x8*)&Ap[BUF][ar * 64 + (kb ^ ((ar & 7) << 3))];     \
      }                                                                        \
      _Pragma("unroll") for (int r = 0; r < 2; ++r) {                          \
        int bc = ni * 32 + r * 16 + lr;                                        \
        bd[r] = *(const s16x8*)&Bp[BUF][bc * 64 + (kb ^ ((bc & 7) << 3))];     \
      }                                                                        \
      bt = *(const s16x8*)&Bp2[BUF][lr * 64 + (kb ^ ((lr & 7) << 3))];         \
      _Pragma("unroll") for (int q = 0; q < 2; ++q) {                          \
        _Pragma("unroll") for (int r = 0; r < 2; ++r)                          \
          acc[q][r] = __builtin_amdgcn_mfma_f32_16x16x32_bf16(af[q], bd[r], acc[q][r], 0, 0, 0); \
        acct2[q] = __builtin_amdgcn_mfma_f32_16x16x32_bf16(af[q], bt, acct2[q], 0, 0, 0); \
      }                                                                        \
    } }

  f32x4 acc[2][2] = {};
  f32x4 acct2[2] = {};
  G2_LOAD(A, 0);
  G2_LOAD(B, 1);
  G2_LOAD(C, 2);
  for (int tt = 0; tt < 12; tt += 6) {
    G2_BODY(0, A, tt + 3);
    G2_BODY(1, B, tt + 4);
    G2_BODY(0, C, tt + 5);
    G2_BODY(1, A, tt + 6);
    G2_BODY(0, B, tt + 7);
    G2_BODY(1, C, tt + 8);
  }
  G2_BODY(0, A, 15);   // tile 12, loads tile 15 into set A
  G2_BODY(1, B, 99);   // tile 13
  G2_BODY(0, C, 99);   // tile 14
  G2_BODY(1, A, 99);   // tile 15
#undef G2_LOAD
#undef G2_BODY

  // ---- epilogue: dump ter2 to LDS, fuse down-LoRA + weight, add into y ----
  __syncthreads();
  float* t2l = (float*)&Ap[0][0];            // 128 x 16 f32
  if (ni == 0) {
#pragma unroll
    for (int q = 0; q < 2; ++q)
#pragma unroll
      for (int j = 0; j < 4; ++j) {
        int row = wr * 32 + q * 16 + lh * 4 + j;
        t2l[row * 16 + lr] = acct2[q][j];
      }
  }
  __syncthreads();
#pragma unroll
  for (int r = 0; r < 2; ++r) {
    int yc = c0 + ni * 32 + r * 16 + lr;
    const float4* d4 = (const float4*)(dlB + ((size_t)e * 2048 + yc) * 16);
    float d2[16];
#pragma unroll
    for (int q = 0; q < 4; ++q) {
      float4 v = d4[q];
      d2[q*4+0]=v.x; d2[q*4+1]=v.y; d2[q*4+2]=v.z; d2[q*4+3]=v.w;
    }
#pragma unroll
    for (int q = 0; q < 2; ++q) {
#pragma unroll
      for (int j = 0; j < 4; ++j) {
        int row = wr * 32 + q * 16 + lh * 4 + j;
        if (st * 128 + row < n) {
          int p = list[e * 512 + st * 128 + row];
          const float* tv = &t2l[row * 16];
          float dd = 0.f;
#pragma unroll
          for (int rr = 0; rr < 16; ++rr) dd += tv[rr] * d2[rr];
          atomicAdd(&y[(size_t)(p >> 1) * 2048 + yc],
                    pw[p] * (acc[q][r][j] + 2.f * dd));
        }
      }
    }
  }
}

// ---------------------------------------------------------------------------
extern "C" void kernel_launch(void* const* d_in, const int* in_sizes, int n_in,
                              void* d_out, int out_size, void* d_ws, size_t ws_size,
                              hipStream_t stream) {
  (void)in_sizes; (void)n_in; (void)ws_size;
  const float* x    = (const float*)d_in[0];
  const float* gw   = (const float*)d_in[1];
  const float* gA   = (const float*)d_in[2];
  const float* gB   = (const float*)d_in[3];
  const float* gup  = (const float*)d_in[4];
  const float* down = (const float*)d_in[5];
  const float* gupA = (const float*)d_in[6];
  const float* gupB = (const float*)d_in[7];
  const float* dlA  = (const float*)d_in[8];
  const float* dlB  = (const float*)d_in[9];
  float* y = (float*)d_out;

  char* w = (char*)d_ws;
  int*   cnt           = (int*)(w + OFF_CNT);
  int*   list          = (int*)(w + OFF_LIST);
  float* pw            = (float*)(w + OFF_PW);
  float* Wg            = (float*)(w + OFF_WG);
  unsigned short* xbf  = (unsigned short*)(w + OFF_XBF);
  unsigned short* hbuf = (unsigned short*)(w + OFF_H);

  hipMemsetAsync(w, 0, ZERO_SPAN, stream);
  hipMemsetAsync(y, 0, (size_t)out_size * sizeof(float), stream);

  k_gatecomb<<<64, 256, 0, stream>>>(gw, gA, gB, Wg);
  k_router<<<512, 256, 0, stream>>>(x, Wg, cnt, list, pw, xbf);
  k_gemm1<<<1024, 512, 0, stream>>>(xbf, gup, gupA, gupB, cnt, list, hbuf);
  k_gemm2<<<1024, 512, 0, stream>>>(hbuf, down, dlA, dlB, cnt, list, pw, y);
}

// Round 16
// 119.667 us; speedup vs baseline: 1.1673x; 1.1673x over previous
//
#include <hip/hip_runtime.h>

// ---------------------------------------------------------------------------
// MoE gated MLP with LoRA, top-2 of 8, T=512, H=2048, I=1024, R=16.
// Round 15: restore R11 (best, 124.5us) + fold the two memsets (cnt, y) into
// k_gatecomb to remove 2 serial dispatches. GEMMs byte-identical to R11.
// ---------------------------------------------------------------------------

typedef short  s16x8 __attribute__((ext_vector_type(8)));
typedef float  f32x4 __attribute__((ext_vector_type(4)));
typedef unsigned short u16x8 __attribute__((ext_vector_type(8)));

__device__ __forceinline__ unsigned short f2bf(float f) {
  unsigned u = __builtin_bit_cast(unsigned, f);
  u += 0x7fffu + ((u >> 16) & 1u);          // RNE
  return (unsigned short)(u >> 16);
}

// Barrier that does NOT drain vmcnt.
#define PIPE_BARRIER() asm volatile("s_waitcnt lgkmcnt(0)\n\ts_barrier" ::: "memory")

// ---- workspace layout (bytes) ----
#define OFF_CNT    0u          // 8 int (pad 256)
#define OFF_LIST   256u        // 8*512 int = 16384
#define OFF_PW     16640u      // 1024 f32 = 4096
#define OFF_WG     20736u      // 8*2048 f32 = 65536
#define OFF_XBF    86272u      // 512*2048 bf16 = 2097152
#define OFF_H      2183424u    // 1024*1024 bf16 = 2097152
// total ~4.3 MB

// ---------------------------------------------------------------------------
// Folds: Wg = gw + 2*gB.gA (router weight), cnt = 0, y = 0.
__global__ void k_gatecomb(const float* __restrict__ gw, const float* __restrict__ gA,
                           const float* __restrict__ gB, float* __restrict__ Wg,
                           int* __restrict__ cnt, float* __restrict__ y) {
  int idx = blockIdx.x * 256 + threadIdx.x;   // 16384
  int e = idx >> 11, h = idx & 2047;
  float acc = gw[idx];
#pragma unroll
  for (int r = 0; r < 16; ++r)
    acc += 2.0f * gB[e * 16 + r] * gA[r * 2048 + h];
  Wg[idx] = acc;
  if (idx < 8) cnt[idx] = 0;
  // zero y: 1,048,576 floats = 262,144 float4; 16 per thread
  float4 z = {0.f, 0.f, 0.f, 0.f};
  float4* y4 = (float4*)y;
#pragma unroll
  for (int q = 0; q < 16; ++q)
    y4[(size_t)q * 16384 + idx] = z;
}

// fp32 router (exact logits -> identical top-k to reference) + fused x->bf16.
__global__ void k_router(const float* __restrict__ x, const float* __restrict__ Wg,
                         int* __restrict__ cnt, int* __restrict__ list,
                         float* __restrict__ pw, unsigned short* __restrict__ xbf) {
  int t = blockIdx.x, tid = threadIdx.x;
  __shared__ float xs[2048];
  __shared__ float logits[8];
  for (int i = tid; i < 2048; i += 256) xs[i] = x[(size_t)t * 2048 + i];
  __syncthreads();
  {
    u16x8 o;
#pragma unroll
    for (int j = 0; j < 8; ++j) o[j] = f2bf(xs[tid * 8 + j]);
    *(u16x8*)(xbf + (size_t)t * 2048 + tid * 8) = o;
  }
  int e = tid >> 5, l = tid & 31;
  float s = 0.f;
  for (int h = l; h < 2048; h += 32) s += xs[h] * Wg[e * 2048 + h];
#pragma unroll
  for (int off = 16; off >= 1; off >>= 1) s += __shfl_down(s, off, 32);
  if (l == 0) logits[e] = s;
  __syncthreads();
  if (tid == 0) {
    float m = logits[0];
#pragma unroll
    for (int i = 1; i < 8; ++i) m = fmaxf(m, logits[i]);
    float ex[8];
#pragma unroll
    for (int i = 0; i < 8; ++i) ex[i] = __expf(logits[i] - m);
    int e1 = 0; float v1 = ex[0];
#pragma unroll
    for (int i = 1; i < 8; ++i) if (ex[i] > v1) { v1 = ex[i]; e1 = i; }
    int e2 = -1; float v2 = -1.f;
#pragma unroll
    for (int i = 0; i < 8; ++i) if (i != e1 && ex[i] > v2) { v2 = ex[i]; e2 = i; }
    float inv = 1.f / (v1 + v2);
    int p1 = 2 * t, p2 = 2 * t + 1;
    pw[p1] = v1 * inv;
    pw[p2] = v2 * inv;
    int s1 = atomicAdd(&cnt[e1], 1); list[e1 * 512 + s1] = p1;
    int s2 = atomicAdd(&cnt[e2], 1); list[e2 * 512 + s2] = p2;
  }
}

// ---------------------------------------------------------------------------
// GEMM1: gathered x rows [BM=128] x gup[e] (64 gate + 64 up cols), full
// K=2048 (NT=32), 3-deep register pipeline. FUSED: ter1 = x . gupA[e] as +2
// MFMA/body with a 16x64 gupA sub-tile (Bp2). Epilogue: silu(g+2dg)*(u+2du).
__global__ __launch_bounds__(512) void k_gemm1(
    const unsigned short* __restrict__ xbf, const float* __restrict__ gup,
    const float* __restrict__ gupA, const float* __restrict__ gupB,
    const int* __restrict__ cnt, const int* __restrict__ list,
    unsigned short* __restrict__ h) {
  const int id = blockIdx.x;                 // 0..511
  const int e  = id & 7;
  const int m  = id >> 3;
  const int ct = m & 15;                     // i-cols [ct*64, ct*64+64)
  const int st = m >> 4;                     // 0..3
  const int n = cnt[e];
  if (st * 128 >= n) return;
  const int tid = threadIdx.x;

  __shared__ unsigned short Ap[2][128 * 64];   // [row][k] swizzled
  __shared__ unsigned short Bp[2][128 * 64];   // [col][k]: 0..63 gate, 64..127 up
  __shared__ unsigned short Bp2[2][16 * 64];   // gupA [r][k]

  const int c0 = ct * 64;

  const unsigned short *aSrc0, *aSrc1;
  int aOff0, aOff1;
  {
    int row = tid >> 3, k16 = tid & 7;
    int p = list[e * 512 + min(st * 128 + row, n - 1)];
    aSrc0 = xbf + (size_t)(p >> 1) * 2048 + k16 * 8;
    aOff0 = row * 64 + ((k16 * 8) ^ ((row & 7) << 3));
    int slot = tid + 512;
    row = slot >> 3; k16 = slot & 7;
    p = list[e * 512 + min(st * 128 + row, n - 1)];
    aSrc1 = xbf + (size_t)(p >> 1) * 2048 + k16 * 8;
    aOff1 = row * 64 + ((k16 * 8) ^ ((row & 7) << 3));
  }
  // B: col 0..127; global col = gate c0+col (col<64) else up 1024+c0+col-64
  const int bcol = tid & 127, kgrp = tid >> 7;   // 4 k-groups of 16
  const int gcg = (bcol < 64) ? (c0 + bcol) : (1024 + c0 + bcol - 64);
  const float* bSrc = gup + (size_t)e * 2048 * 2048 + (size_t)(kgrp * 16) * 2048 + gcg;
  const int sw = (bcol & 7) << 3;
  const int bOff0 = bcol * 64 + ((kgrp * 16) ^ sw);
  const int bOff1 = bcol * 64 + ((kgrp * 16 + 8) ^ sw);

  // gupA sub-tile staging (threads 0..127): 16 r x 8 k-chunks
  const int gr = (tid >> 3) & 15, gk = tid & 7;
  const float* gaSrc = gupA + ((size_t)e * 16 + gr) * 2048 + gk * 8;
  const int gaOff = gr * 64 + ((gk * 8) ^ ((gr & 7) << 3));

  const int lane = tid & 63, wv = tid >> 6;
  const int lr = lane & 15, lh = lane >> 4;
  const int wr = wv >> 1, ni = wv & 1;       // 4 M-waves x 2 N-waves

  uint4 a0A, a1A, a0B, a1B, a0C, a1C;
  float bA[16], bB[16], bC[16];
  float4 g0A, g1A, g0B, g1B, g0C, g1C;

#define G1_LOAD(SUF, T) {                                        \
    const int kk = (T) * 64;                                     \
    a0##SUF = *(const uint4*)(aSrc0 + kk);                       \
    a1##SUF = *(const uint4*)(aSrc1 + kk);                       \
    _Pragma("unroll") for (int j = 0; j < 16; ++j)               \
      b##SUF[j] = bSrc[(size_t)(kk + j) * 2048];                 \
    if (tid < 128) {                                             \
      g0##SUF = *(const float4*)(gaSrc + kk);                    \
      g1##SUF = *(const float4*)(gaSrc + kk + 4); } }

#define G1_BODY(BUF, SUF, NXT) {                                               \
    *(uint4*)&Ap[BUF][aOff0] = a0##SUF;                                        \
    *(uint4*)&Ap[BUF][aOff1] = a1##SUF;                                        \
    { u16x8 o0, o1;                                                            \
      _Pragma("unroll") for (int j = 0; j < 8; ++j) {                          \
        o0[j] = f2bf(b##SUF[j]); o1[j] = f2bf(b##SUF[j + 8]); }                \
      *(u16x8*)&Bp[BUF][bOff0] = o0;                                           \
      *(u16x8*)&Bp[BUF][bOff1] = o1; }                                         \
    if (tid < 128) { u16x8 og;                                                 \
      og[0]=f2bf(g0##SUF.x); og[1]=f2bf(g0##SUF.y);                            \
      og[2]=f2bf(g0##SUF.z); og[3]=f2bf(g0##SUF.w);                            \
      og[4]=f2bf(g1##SUF.x); og[5]=f2bf(g1##SUF.y);                            \
      og[6]=f2bf(g1##SUF.z); og[7]=f2bf(g1##SUF.w);                            \
      *(u16x8*)&Bp2[BUF][gaOff] = og; }                                        \
    PIPE_BARRIER();                                                            \
    if ((NXT) < 32) G1_LOAD(SUF, NXT);                                         \
    _Pragma("unroll") for (int ks = 0; ks < 64; ks += 32) {                    \
      int kb = ks + lh * 8;                                                    \
      s16x8 af[2], bg[2], bu[2], bt;                                           \
      _Pragma("unroll") for (int q = 0; q < 2; ++q) {                          \
        int ar = wr * 32 + q * 16 + lr;                                        \
        af[q] = *(const s16x8*)&Ap[BUF][ar * 64 + (kb ^ ((ar & 7) << 3))];     \
      }                                                                        \
      _Pragma("unroll") for (int r = 0; r < 2; ++r) {                          \
        int bc = ni * 32 + r * 16 + lr;                                        \
        bg[r] = *(const s16x8*)&Bp[BUF][bc * 64 + (kb ^ ((bc & 7) << 3))];     \
        bu[r] = *(const s16x8*)&Bp[BUF][(bc + 64) * 64 + (kb ^ ((bc & 7) << 3))]; \
      }                                                                        \
      bt = *(const s16x8*)&Bp2[BUF][lr * 64 + (kb ^ ((lr & 7) << 3))];         \
      _Pragma("unroll") for (int q = 0; q < 2; ++q) {                          \
        _Pragma("unroll") for (int r = 0; r < 2; ++r) {                        \
          accg[q][r] = __builtin_amdgcn_mfma_f32_16x16x32_bf16(af[q], bg[r], accg[q][r], 0, 0, 0); \
          accu[q][r] = __builtin_amdgcn_mfma_f32_16x16x32_bf16(af[q], bu[r], accu[q][r], 0, 0, 0); \
        }                                                                      \
        acct1[q] = __builtin_amdgcn_mfma_f32_16x16x32_bf16(af[q], bt, acct1[q], 0, 0, 0); \
      }                                                                        \
    } }

  f32x4 accg[2][2] = {}, accu[2][2] = {};
  f32x4 acct1[2] = {};
  G1_LOAD(A, 0);
  G1_LOAD(B, 1);
  G1_LOAD(C, 2);
  for (int tt = 0; tt < 30; tt += 6) {
    G1_BODY(0, A, tt + 3);
    G1_BODY(1, B, tt + 4);
    G1_BODY(0, C, tt + 5);
    G1_BODY(1, A, tt + 6);
    G1_BODY(0, B, tt + 7);
    G1_BODY(1, C, tt + 8);
  }
  G1_BODY(0, A, 99);   // tile 30
  G1_BODY(1, B, 99);   // tile 31
#undef G1_LOAD
#undef G1_BODY

  // ---- epilogue: dump in-register ter1 to LDS, fuse LoRA + silu, store h ----
  __syncthreads();
  float* tlds = (float*)&Ap[0][0];             // 128 x 16 f32
  if (ni == 0) {
#pragma unroll
    for (int q = 0; q < 2; ++q)
#pragma unroll
      for (int j = 0; j < 4; ++j) {
        int row = wr * 32 + q * 16 + lh * 4 + j;
        tlds[row * 16 + lr] = acct1[q][j];
      }
  }
  __syncthreads();
#pragma unroll
  for (int r = 0; r < 2; ++r) {
    int gc = c0 + ni * 32 + r * 16 + lr;       // global i-col 0..1023
    const float4* g4 = (const float4*)(gupB + ((size_t)e * 2048 + gc) * 16);
    const float4* u4 = (const float4*)(gupB + ((size_t)e * 2048 + 1024 + gc) * 16);
    float gv2[16], uv2[16];
#pragma unroll
    for (int q = 0; q < 4; ++q) {
      float4 gv = g4[q], uv = u4[q];
      gv2[q*4+0]=gv.x; gv2[q*4+1]=gv.y; gv2[q*4+2]=gv.z; gv2[q*4+3]=gv.w;
      uv2[q*4+0]=uv.x; uv2[q*4+1]=uv.y; uv2[q*4+2]=uv.z; uv2[q*4+3]=uv.w;
    }
#pragma unroll
    for (int q = 0; q < 2; ++q) {
#pragma unroll
      for (int j = 0; j < 4; ++j) {
        int row = wr * 32 + q * 16 + lh * 4 + j;
        if (st * 128 + row < n) {
          int p = list[e * 512 + st * 128 + row];
          const float* tv = &tlds[row * 16];
          float dg = 0.f, du = 0.f;
#pragma unroll
          for (int rr = 0; rr < 16; ++rr) { dg += tv[rr] * gv2[rr]; du += tv[rr] * uv2[rr]; }
          float g = accg[q][r][j] + 2.f * dg;
          float u = accu[q][r][j] + 2.f * du;
          h[(size_t)p * 1024 + gc] = f2bf(g / (1.f + __expf(-g)) * u);
        }
      }
    }
  }
}

// ---------------------------------------------------------------------------
// GEMM2: gathered h rows [BM=128] x down[e] [BN=64], full K=1024 (NT=16),
// 3-deep pipeline. FUSED: ter2 = h . dlA[e] as +2 MFMA/body (Bp2 tile).
// Epilogue fuses down-LoRA + routing weight; atomicAdd into zeroed y.
__global__ __launch_bounds__(512) void k_gemm2(
    const unsigned short* __restrict__ h, const float* __restrict__ down,
    const float* __restrict__ dlA, const float* __restrict__ dlB,
    const int* __restrict__ cnt, const int* __restrict__ list,
    const float* __restrict__ pw, float* __restrict__ y) {
  const int id = blockIdx.x;                 // 0..1023
  const int e  = id & 7;
  const int m  = id >> 3;
  const int ct = m & 31;                     // 0..31
  const int st = m >> 5;                     // 0..3
  const int n = cnt[e];
  if (st * 128 >= n) return;
  const int tid = threadIdx.x;

  __shared__ unsigned short Ap[2][128 * 64];
  __shared__ unsigned short Bp[2][64 * 64];
  __shared__ unsigned short Bp2[2][16 * 64];   // dlA [r][k]

  const int c0 = ct * 64;

  const unsigned short *aSrc0, *aSrc1;
  int aOff0, aOff1;
  {
    int row = tid >> 3, k16 = tid & 7;
    int p = list[e * 512 + min(st * 128 + row, n - 1)];
    aSrc0 = h + (size_t)p * 1024 + k16 * 8;
    aOff0 = row * 64 + ((k16 * 8) ^ ((row & 7) << 3));
    int slot = tid + 512;
    row = slot >> 3; k16 = slot & 7;
    p = list[e * 512 + min(st * 128 + row, n - 1)];
    aSrc1 = h + (size_t)p * 1024 + k16 * 8;
    aOff1 = row * 64 + ((k16 * 8) ^ ((row & 7) << 3));
  }
  const int bcol = tid & 63, kg = tid >> 6;  // 8 k-groups of 8
  const float* bSrc = down + (size_t)e * 1024 * 2048 + (size_t)(kg * 8) * 2048 + c0 + bcol;
  const int bOff = bcol * 64 + ((kg * 8) ^ ((bcol & 7) << 3));

  // dlA sub-tile staging (threads 0..127): 16 r x 8 k-chunks
  const int gr = (tid >> 3) & 15, gk = tid & 7;
  const float* gaSrc = dlA + ((size_t)e * 16 + gr) * 1024 + gk * 8;
  const int gaOff = gr * 64 + ((gk * 8) ^ ((gr & 7) << 3));

  const int lane = tid & 63, wv = tid >> 6;
  const int lr = lane & 15, lh = lane >> 4;
  const int wr = wv >> 1, ni = wv & 1;

  uint4 a0A, a1A, a0B, a1B, a0C, a1C;
  float bA[8], bB[8], bC[8];
  float4 g0A, g1A, g0B, g1B, g0C, g1C;

#define G2_LOAD(SUF, T) {                                        \
    const int kk = (T) * 64;                                     \
    a0##SUF = *(const uint4*)(aSrc0 + kk);                       \
    a1##SUF = *(const uint4*)(aSrc1 + kk);                       \
    _Pragma("unroll") for (int j = 0; j < 8; ++j)                \
      b##SUF[j] = bSrc[(size_t)(kk + j) * 2048];                 \
    if (tid < 128) {                                             \
      g0##SUF = *(const float4*)(gaSrc + kk);                    \
      g1##SUF = *(const float4*)(gaSrc + kk + 4); } }

#define G2_BODY(BUF, SUF, NXT) {                                               \
    *(uint4*)&Ap[BUF][aOff0] = a0##SUF;                                        \
    *(uint4*)&Ap[BUF][aOff1] = a1##SUF;                                        \
    { u16x8 o;                                                                 \
      _Pragma("unroll") for (int j = 0; j < 8; ++j) o[j] = f2bf(b##SUF[j]);    \
      *(u16x8*)&Bp[BUF][bOff] = o; }                                           \
    if (tid < 128) { u16x8 og;                                                 \
      og[0]=f2bf(g0##SUF.x); og[1]=f2bf(g0##SUF.y);                            \
      og[2]=f2bf(g0##SUF.z); og[3]=f2bf(g0##SUF.w);                            \
      og[4]=f2bf(g1##SUF.x); og[5]=f2bf(g1##SUF.y);                            \
      og[6]=f2bf(g1##SUF.z); og[7]=f2bf(g1##SUF.w);                            \
      *(u16x8*)&Bp2[BUF][gaOff] = og; }                                        \
    PIPE_BARRIER();                                                            \
    if ((NXT) < 16) G2_LOAD(SUF, NXT);                                         \
    _Pragma("unroll") for (int ks = 0; ks < 64; ks += 32) {                    \
      int kb = ks + lh * 8;                                                    \
      s16x8 af[2], bd[2], bt;                                                  \
      _Pragma("unroll") for (int q = 0; q < 2; ++q) {                          \
        int ar = wr * 32 + q * 16 + lr;                                        \
        af[q] = *(const s16x8*)&Ap[BUF][ar * 64 + (kb ^ ((ar & 7) << 3))];     \
      }                                                                        \
      _Pragma("unroll") for (int r = 0; r < 2; ++r) {                          \
        int bc = ni * 32 + r * 16 + lr;                                        \
        bd[r] = *(const s16x8*)&Bp[BUF][bc * 64 + (kb ^ ((bc & 7) << 3))];     \
      }                                                                        \
      bt = *(const s16x8*)&Bp2[BUF][lr * 64 + (kb ^ ((lr & 7) << 3))];         \
      _Pragma("unroll") for (int q = 0; q < 2; ++q) {                          \
        _Pragma("unroll") for (int r = 0; r < 2; ++r)                          \
          acc[q][r] = __builtin_amdgcn_mfma_f32_16x16x32_bf16(af[q], bd[r], acc[q][r], 0, 0, 0); \
        acct2[q] = __builtin_amdgcn_mfma_f32_16x16x32_bf16(af[q], bt, acct2[q], 0, 0, 0); \
      }                                                                        \
    } }

  f32x4 acc[2][2] = {};
  f32x4 acct2[2] = {};
  G2_LOAD(A, 0);
  G2_LOAD(B, 1);
  G2_LOAD(C, 2);
  for (int tt = 0; tt < 12; tt += 6) {
    G2_BODY(0, A, tt + 3);
    G2_BODY(1, B, tt + 4);
    G2_BODY(0, C, tt + 5);
    G2_BODY(1, A, tt + 6);
    G2_BODY(0, B, tt + 7);
    G2_BODY(1, C, tt + 8);
  }
  G2_BODY(0, A, 15);   // tile 12, loads tile 15 into set A
  G2_BODY(1, B, 99);   // tile 13
  G2_BODY(0, C, 99);   // tile 14
  G2_BODY(1, A, 99);   // tile 15
#undef G2_LOAD
#undef G2_BODY

  // ---- epilogue: dump ter2 to LDS, fuse down-LoRA + weight, add into y ----
  __syncthreads();
  float* t2l = (float*)&Ap[0][0];            // 128 x 16 f32
  if (ni == 0) {
#pragma unroll
    for (int q = 0; q < 2; ++q)
#pragma unroll
      for (int j = 0; j < 4; ++j) {
        int row = wr * 32 + q * 16 + lh * 4 + j;
        t2l[row * 16 + lr] = acct2[q][j];
      }
  }
  __syncthreads();
#pragma unroll
  for (int r = 0; r < 2; ++r) {
    int yc = c0 + ni * 32 + r * 16 + lr;
    const float4* d4 = (const float4*)(dlB + ((size_t)e * 2048 + yc) * 16);
    float d2[16];
#pragma unroll
    for (int q = 0; q < 4; ++q) {
      float4 v = d4[q];
      d2[q*4+0]=v.x; d2[q*4+1]=v.y; d2[q*4+2]=v.z; d2[q*4+3]=v.w;
    }
#pragma unroll
    for (int q = 0; q < 2; ++q) {
#pragma unroll
      for (int j = 0; j < 4; ++j) {
        int row = wr * 32 + q * 16 + lh * 4 + j;
        if (st * 128 + row < n) {
          int p = list[e * 512 + st * 128 + row];
          const float* tv = &t2l[row * 16];
          float dd = 0.f;
#pragma unroll
          for (int rr = 0; rr < 16; ++rr) dd += tv[rr] * d2[rr];
          atomicAdd(&y[(size_t)(p >> 1) * 2048 + yc],
                    pw[p] * (acc[q][r][j] + 2.f * dd));
        }
      }
    }
  }
}

// ---------------------------------------------------------------------------
extern "C" void kernel_launch(void* const* d_in, const int* in_sizes, int n_in,
                              void* d_out, int out_size, void* d_ws, size_t ws_size,
                              hipStream_t stream) {
  (void)in_sizes; (void)n_in; (void)ws_size; (void)out_size;
  const float* x    = (const float*)d_in[0];
  const float* gw   = (const float*)d_in[1];
  const float* gA   = (const float*)d_in[2];
  const float* gB   = (const float*)d_in[3];
  const float* gup  = (const float*)d_in[4];
  const float* down = (const float*)d_in[5];
  const float* gupA = (const float*)d_in[6];
  const float* gupB = (const float*)d_in[7];
  const float* dlA  = (const float*)d_in[8];
  const float* dlB  = (const float*)d_in[9];
  float* y = (float*)d_out;

  char* w = (char*)d_ws;
  int*   cnt           = (int*)(w + OFF_CNT);
  int*   list          = (int*)(w + OFF_LIST);
  float* pw            = (float*)(w + OFF_PW);
  float* Wg            = (float*)(w + OFF_WG);
  unsigned short* xbf  = (unsigned short*)(w + OFF_XBF);
  unsigned short* hbuf = (unsigned short*)(w + OFF_H);

  k_gatecomb<<<64, 256, 0, stream>>>(gw, gA, gB, Wg, cnt, y);
  k_router<<<512, 256, 0, stream>>>(x, Wg, cnt, list, pw, xbf);
  k_gemm1<<<512, 512, 0, stream>>>(xbf, gup, gupA, gupB, cnt, list, hbuf);
  k_gemm2<<<1024, 512, 0, stream>>>(hbuf, down, dlA, dlB, cnt, list, pw, y);
}